// Round 5
// baseline (936.974 us; speedup 1.0000x reference)
//
#include <hip/hip_runtime.h>
#include <math.h>

// ---------------------------------------------------------------------------
// Types
// ---------------------------------------------------------------------------
typedef _Float16 half8 __attribute__((ext_vector_type(8)));
typedef float f32x4 __attribute__((ext_vector_type(4)));

struct FreqT { float f[16]; };

__device__ __forceinline__ f32x4 mfma16(half8 a, half8 b, f32x4 c) {
  return __builtin_amdgcn_mfma_f32_16x16x32_f16(a, b, c, 0, 0, 0);
}

__device__ __forceinline__ void gload_lds16(const void* g, void* l) {
  __builtin_amdgcn_global_load_lds(
      (const __attribute__((address_space(1))) void*)g,
      (__attribute__((address_space(3))) void*)l, 16, 0, 0);
}

#define S_BARRIER() __builtin_amdgcn_s_barrier()
#define WAIT_LGKM0() asm volatile("s_waitcnt lgkmcnt(0)" ::: "memory")
#define WAIT_VM8() asm volatile("s_waitcnt vmcnt(8)" ::: "memory")
#define WAIT_VM0() asm volatile("s_waitcnt vmcnt(0)" ::: "memory")

// ---------------------------------------------------------------------------
// Cast fp32 -> fp16, 8 elems/thread
// ---------------------------------------------------------------------------
__global__ __launch_bounds__(256)
void cast_f32_f16(const float* __restrict__ in, _Float16* __restrict__ out, long n8) {
  long i = (long)blockIdx.x * blockDim.x + threadIdx.x;
  if (i >= n8) return;
  float4 a = ((const float4*)in)[2 * i];
  float4 b = ((const float4*)in)[2 * i + 1];
  half8 v;
  v[0] = (_Float16)a.x; v[1] = (_Float16)a.y; v[2] = (_Float16)a.z; v[3] = (_Float16)a.w;
  v[4] = (_Float16)b.x; v[5] = (_Float16)b.y; v[6] = (_Float16)b.z; v[7] = (_Float16)b.w;
  ((half8*)out)[i] = v;
}

// ---------------------------------------------------------------------------
// GEMM 256x256x64, 8 waves (2M x 4N), deep pipeline with counted vmcnt.
// C[M,N] = A[M,K] @ W[N,K]^T + bias.  LDS tiles XOR-swizzled (col ^= (row&7)<<3)
// via pre-swizzled global_load_lds source; ds_read applies the same involution.
// ---------------------------------------------------------------------------
#define GBM 256
#define GBN 256
#define GBK 64

template <typename OutT>
__global__ __launch_bounds__(512, 2)
void gemm256(const _Float16* __restrict__ A, const _Float16* __restrict__ W,
             const float* __restrict__ bias, OutT* __restrict__ C,
             int M, int N, int K) {
  // [buf][A/B][256*64] : 128 KiB total
  __shared__ __align__(16) _Float16 lds[4][GBM * GBK];

  int nwg = gridDim.x;
  int bid = blockIdx.x;
  int cpx = nwg >> 3;
  int swz = (bid & 7) * cpx + (bid >> 3);
  int ntn = N / GBN;
  int m0 = (swz / ntn) * GBM, n0 = (swz % ntn) * GBN;

  int tid = threadIdx.x, lane = tid & 63, w = tid >> 6;
  int wm = w >> 2, wn = w & 3;          // wave grid 2M x 4N
  int g = lane >> 4, lc = lane & 15;

  // --- staging addressing: lane l covers row (chunk + w*8 + l>>3), 16B slot l&7,
  //     global col pre-swizzled so linear LDS dest ends up swizzled.
  int r8 = w * 8 + (lane >> 3);
  int cs = (((lane & 7) ^ (lane >> 3)) << 3);
  const _Float16* gA = A + (size_t)(m0 + r8) * K + cs;
  const _Float16* gB = W + (size_t)(n0 + r8) * K + cs;

#define STAGE(bi, k0) do {                                            \
    _Float16* la_ = &lds[(bi) * 2][0] + w * 512;                      \
    _Float16* lb_ = &lds[(bi) * 2 + 1][0] + w * 512;                  \
    _Pragma("unroll")                                                 \
    for (int i_ = 0; i_ < 4; ++i_) {                                  \
      gload_lds16(gA + (size_t)(i_ * 64) * K + (k0), la_ + i_ * 4096);\
      gload_lds16(gB + (size_t)(i_ * 64) * K + (k0), lb_ + i_ * 4096);\
    } } while (0)

  // --- fragment read offsets (f16 units). row&7 == lc&7 for all frags.
  int aOff[8], bOff[4];
#pragma unroll
  for (int mf = 0; mf < 8; ++mf) aOff[mf] = (wm * 128 + mf * 16 + lc) * 64;
#pragma unroll
  for (int nf = 0; nf < 4; ++nf) bOff[nf] = (wn * 64 + nf * 16 + lc) * 64;
  int co0 = (((0 * 4 + g) ^ (lc & 7)) << 3);
  int co1 = (((1 * 4 + g) ^ (lc & 7)) << 3);

  half8 a0[8], a1[8], b0[4], b1[4];  // [frag*2 + kk]
  f32x4 acc[8][4] = {};

#define LOAD_SET0(bi) do {                                            \
    const _Float16* lA_ = &lds[(bi) * 2][0];                          \
    const _Float16* lB_ = &lds[(bi) * 2 + 1][0];                      \
    _Pragma("unroll")                                                 \
    for (int mf = 0; mf < 4; ++mf) {                                  \
      a0[mf * 2 + 0] = *(const half8*)&lA_[aOff[mf] + co0];           \
      a0[mf * 2 + 1] = *(const half8*)&lA_[aOff[mf] + co1];           \
    }                                                                 \
    _Pragma("unroll")                                                 \
    for (int nf = 0; nf < 2; ++nf) {                                  \
      b0[nf * 2 + 0] = *(const half8*)&lB_[bOff[nf] + co0];           \
      b0[nf * 2 + 1] = *(const half8*)&lB_[bOff[nf] + co1];           \
    } } while (0)

#define LOAD_SET1(bi) do {                                            \
    const _Float16* lA_ = &lds[(bi) * 2][0];                          \
    const _Float16* lB_ = &lds[(bi) * 2 + 1][0];                      \
    _Pragma("unroll")                                                 \
    for (int mf = 0; mf < 4; ++mf) {                                  \
      a1[mf * 2 + 0] = *(const half8*)&lA_[aOff[mf + 4] + co0];       \
      a1[mf * 2 + 1] = *(const half8*)&lA_[aOff[mf + 4] + co1];       \
    }                                                                 \
    _Pragma("unroll")                                                 \
    for (int nf = 0; nf < 2; ++nf) {                                  \
      b1[nf * 2 + 0] = *(const half8*)&lB_[bOff[nf + 2] + co0];       \
      b1[nf * 2 + 1] = *(const half8*)&lB_[bOff[nf + 2] + co1];       \
    } } while (0)

#define MFMA_Q(mq, nq, ar, br) do {                                   \
    __builtin_amdgcn_s_setprio(1);                                    \
    _Pragma("unroll")                                                 \
    for (int mf = 0; mf < 4; ++mf)                                    \
      _Pragma("unroll")                                               \
      for (int nf = 0; nf < 2; ++nf)                                  \
        _Pragma("unroll")                                             \
        for (int kk = 0; kk < 2; ++kk)                                \
          acc[(mq) * 4 + mf][(nq) * 2 + nf] =                         \
              mfma16(ar[mf * 2 + kk], br[nf * 2 + kk],                \
                     acc[(mq) * 4 + mf][(nq) * 2 + nf]);              \
    __builtin_amdgcn_s_setprio(0); } while (0)

  const int NT = K >> 6;  // K/64, >= 3

  // prologue: stage tiles 0,1; wait tile 0; read its first frag set
  STAGE(0, 0);
  STAGE(1, GBK);
  WAIT_VM8();
  S_BARRIER();
  LOAD_SET0(0);

  for (int t = 0; t < NT - 2; ++t) {
    int cur = t & 1;
    LOAD_SET1(cur);                // remaining 12 frags of tile t
    MFMA_Q(0, 0, a0, b0);
    MFMA_Q(0, 1, a0, b1);
    WAIT_LGKM0();                  // all my reads of buf[cur] done
    S_BARRIER();                   // ... and everyone else's
    STAGE(cur, (t + 2) << 6);      // prefetch tile t+2 into freed buffer
    MFMA_Q(1, 1, a1, b1);
    MFMA_Q(1, 0, a1, b0);
    WAIT_VM8();                    // tile t+1 resident (t+2's 8 stay in flight)
    S_BARRIER();
    LOAD_SET0(cur ^ 1);            // first frag set of tile t+1
  }
  {  // t = NT-2: no more staging; drain to tile NT-1
    int cur = (NT - 2) & 1;
    LOAD_SET1(cur);
    MFMA_Q(0, 0, a0, b0);
    MFMA_Q(0, 1, a0, b1);
    MFMA_Q(1, 1, a1, b1);
    MFMA_Q(1, 0, a1, b0);
    WAIT_VM0();
    S_BARRIER();
    LOAD_SET0(cur ^ 1);
  }
  {  // t = NT-1
    int cur = (NT - 1) & 1;
    LOAD_SET1(cur);
    MFMA_Q(0, 0, a0, b0);
    MFMA_Q(0, 1, a0, b1);
    MFMA_Q(1, 1, a1, b1);
    MFMA_Q(1, 0, a1, b0);
  }

  // epilogue
  int crow = m0 + wm * 128 + g * 4;
  int ccol = n0 + wn * 64 + lc;
#pragma unroll
  for (int nf = 0; nf < 4; ++nf) {
    float bv = bias[ccol + nf * 16];
#pragma unroll
    for (int mf = 0; mf < 8; ++mf)
#pragma unroll
      for (int j = 0; j < 4; ++j)
        C[(size_t)(crow + mf * 16 + j) * N + ccol + nf * 16] =
            (OutT)(acc[mf][nf][j] + bv);
  }
#undef STAGE
#undef LOAD_SET0
#undef LOAD_SET1
#undef MFMA_Q
}

// ---------------------------------------------------------------------------
// RoPE (faithful to the reference's fp32 overflow-to-zero freqs, dim=n_heads)
// ---------------------------------------------------------------------------
__global__ __launch_bounds__(256)
void rope_kernel(_Float16* __restrict__ x, FreqT ft, int Sn, int E, long n8) {
  long i = (long)blockIdx.x * blockDim.x + threadIdx.x;
  if (i >= n8) return;
  int epr = E / 8;
  int e8 = (int)(i % epr);
  int s = (int)((i / epr) % Sn);
  int fj = e8 & 15;
  float fr = ft.f[fj];
  float ang = (float)s * fr;
  float sv, cv;
  sincosf(ang, &sv, &cv);
  half8 v = ((const half8*)x)[i];
  half8 o;
#pragma unroll
  for (int p = 0; p < 4; ++p) {
    float x1 = (float)v[2 * p], x2 = (float)v[2 * p + 1];
    o[2 * p] = (_Float16)(x1 * cv - x2 * sv);
    o[2 * p + 1] = (_Float16)(x1 * sv + x2 * cv);
  }
  ((half8*)x)[i] = o;
}

// ---------------------------------------------------------------------------
// Flash attention (non-causal). D=128. 256 threads = 4 waves. (unchanged)
// ---------------------------------------------------------------------------
#define QB 128
#define KB 64

__global__ __launch_bounds__(256)
void flash_attn(const _Float16* __restrict__ qg, const _Float16* __restrict__ kg,
                const _Float16* __restrict__ vg, _Float16* __restrict__ og,
                int Bn, int Hn, int Sn) {
  const int D = 128;
  const int E = Hn * D;

  __shared__ _Float16 Ksh[KB * 128];
  __shared__ _Float16 Vsh[128 * 64];
  __shared__ _Float16 Psh[4 * 32 * 64];

  int qtiles = Sn / QB;
  int bid = blockIdx.x;
  int bh = bid / qtiles, qt = bid % qtiles;
  int b = bh / Hn, h = bh % Hn;

  int tid = threadIdx.x, lane = tid & 63, w = tid >> 6;
  int g = lane >> 4, lc = lane & 15;
  int lc7 = lc & 7;

  const size_t headoff = ((size_t)b * Sn) * E + (size_t)h * D;
  const _Float16* qp = qg + headoff;
  const _Float16* kp = kg + headoff;
  const _Float16* vp = vg + headoff;

  int q0 = qt * QB + w * 32;
  half8 aq[2][4];
#pragma unroll
  for (int mf = 0; mf < 2; ++mf)
#pragma unroll
    for (int kf = 0; kf < 4; ++kf)
      aq[mf][kf] = *(const half8*)(qp + (size_t)(q0 + mf * 16 + lc) * E + kf * 32 + g * 8);

  float mrun[2][4], lpart[2][4];
  f32x4 o[2][8] = {};
#pragma unroll
  for (int mf = 0; mf < 2; ++mf)
#pragma unroll
    for (int j = 0; j < 4; ++j) { mrun[mf][j] = -1e30f; lpart[mf][j] = 0.f; }

  const float scale = 0.08838834764831845f;

  int krow = 4 * w + (lane >> 4);
  int kcol = ((lane & 15) ^ (krow & 7)) * 8;
  const _Float16* gK = kp + (size_t)krow * E + kcol;
  _Float16* lK = Ksh + w * 512;

  half8 vreg[4];
#pragma unroll
  for (int p = 0; p < 4; ++p)
    vreg[p] = *(const half8*)(vp + (size_t)lane * E + p * 32 + w * 8);

  int kvlo = lane & 7, kvhi = lane >> 3;
  _Float16* Pw = Psh + w * 2048;

  const int NT = Sn / KB;
  for (int kt = 0; kt < NT; ++kt) {
    __syncthreads();
#pragma unroll
    for (int i = 0; i < 4; ++i)
      gload_lds16(gK + (size_t)(kt * KB + 16 * i) * E, lK + i * 2048);
#pragma unroll
    for (int p = 0; p < 4; ++p) {
      int d0 = p * 32 + w * 8;
#pragma unroll
      for (int i = 0; i < 8; ++i)
        Vsh[(d0 + i) * 64 + (kvlo | (((kvhi ^ i) & 7) << 3))] = vreg[p][i];
    }
    __syncthreads();

    f32x4 s[2][4] = {};
    __builtin_amdgcn_s_setprio(1);
#pragma unroll
    for (int kf = 0; kf < 4; ++kf) {
      half8 bk[4];
#pragma unroll
      for (int nf = 0; nf < 4; ++nf)
        bk[nf] = *(const half8*)&Ksh[(nf * 16 + lc) * 128 + (((kf * 4 + g) ^ lc7) << 3)];
#pragma unroll
      for (int mf = 0; mf < 2; ++mf)
#pragma unroll
        for (int nf = 0; nf < 4; ++nf)
          s[mf][nf] = mfma16(aq[mf][kf], bk[nf], s[mf][nf]);
    }
    __builtin_amdgcn_s_setprio(0);

#pragma unroll
    for (int mf = 0; mf < 2; ++mf) {
      f32x4 mx = s[mf][0];
#pragma unroll
      for (int nf = 1; nf < 4; ++nf)
#pragma unroll
        for (int j = 0; j < 4; ++j) mx[j] = fmaxf(mx[j], s[mf][nf][j]);
#pragma unroll
      for (int d = 1; d < 16; d <<= 1)
#pragma unroll
        for (int j = 0; j < 4; ++j) mx[j] = fmaxf(mx[j], __shfl_xor(mx[j], d));
      bool need = false;
#pragma unroll
      for (int j = 0; j < 4; ++j) need |= (mx[j] * scale > mrun[mf][j] + 8.f);
      if (__any(need)) {
#pragma unroll
        for (int j = 0; j < 4; ++j) {
          float mnew = fmaxf(mrun[mf][j], mx[j] * scale);
          float r = __expf(mrun[mf][j] - mnew);
          mrun[mf][j] = mnew;
          lpart[mf][j] *= r;
#pragma unroll
          for (int df = 0; df < 8; ++df) o[mf][df][j] *= r;
        }
      }
#pragma unroll
      for (int nf = 0; nf < 4; ++nf) {
        int colbase = nf * 16 + lc;
        int chi = colbase >> 3, clo = colbase & 7;
#pragma unroll
        for (int j = 0; j < 4; ++j) {
          float p = __expf(s[mf][nf][j] * scale - mrun[mf][j]);
          lpart[mf][j] += p;
          int row = mf * 16 + g * 4 + j;
          Pw[row * 64 + (clo | (((chi ^ (row & 7)) & 7) << 3))] = (_Float16)p;
        }
      }
    }

    if (kt + 1 < NT) {
#pragma unroll
      for (int p = 0; p < 4; ++p)
        vreg[p] = *(const half8*)(vp + (size_t)((kt + 1) * KB + lane) * E + p * 32 + w * 8);
    }

    __builtin_amdgcn_s_setprio(1);
#pragma unroll
    for (int kk = 0; kk < 2; ++kk) {
      half8 ap0 = *(const half8*)&Pw[lc * 64 + (((kk * 4 + g) ^ lc7) << 3)];
      half8 ap1 = *(const half8*)&Pw[(16 + lc) * 64 + (((kk * 4 + g) ^ lc7) << 3)];
#pragma unroll
      for (int df = 0; df < 8; ++df) {
        half8 bv = *(const half8*)&Vsh[(df * 16 + lc) * 64 + (((kk * 4 + g) ^ lc7) << 3)];
        o[0][df] = mfma16(ap0, bv, o[0][df]);
        o[1][df] = mfma16(ap1, bv, o[1][df]);
      }
    }
    __builtin_amdgcn_s_setprio(0);
  }

  _Float16* op = og + headoff;
#pragma unroll
  for (int mf = 0; mf < 2; ++mf) {
#pragma unroll
    for (int j = 0; j < 4; ++j) {
      float l = lpart[mf][j];
#pragma unroll
      for (int d = 1; d < 16; d <<= 1) l += __shfl_xor(l, d);
      float inv = 1.0f / l;
      int row = q0 + mf * 16 + g * 4 + j;
#pragma unroll
      for (int df = 0; df < 8; ++df)
        op[(size_t)row * E + df * 16 + lc] = (_Float16)(o[mf][df][j] * inv);
    }
  }
}

// ---------------------------------------------------------------------------
// Launch
// ---------------------------------------------------------------------------
extern "C" void kernel_launch(void* const* d_in, const int* in_sizes, int n_in,
                              void* d_out, int out_size, void* d_ws, size_t ws_size,
                              hipStream_t stream) {
  const float* x  = (const float*)d_in[0];
  const float* Wq = (const float*)d_in[1];
  const float* bq = (const float*)d_in[2];
  const float* Wk = (const float*)d_in[3];
  const float* bk = (const float*)d_in[4];
  const float* Wv = (const float*)d_in[5];
  const float* bv = (const float*)d_in[6];
  const float* Wo = (const float*)d_in[7];
  const float* bo = (const float*)d_in[8];

  const int E = in_sizes[2];        // 4096
  const int M = in_sizes[0] / E;    // B*S = 4096
  const int S = 2048;
  const int Bb = M / S;             // 2
  const int H = 32;

  _Float16* xh = (_Float16*)d_ws;               // M*E (reused as attn-out)
  _Float16* wh = xh + (size_t)M * E;            // E*E
  _Float16* qh = wh + (size_t)E * E;            // M*E
  _Float16* kh = qh + (size_t)M * E;
  _Float16* vh = kh + (size_t)M * E;
  _Float16* oh = xh;

  FreqT ft;
  for (int j = 0; j < 16; ++j) {
    float pf = (float)pow(10000.0, (double)(2 * j));  // inf for j>=5 (faithful)
    ft.f[j] = 1.0f / (pf / 32.0f);
  }

  long nx8 = (long)M * E / 8;
  long nw8 = (long)E * E / 8;
  dim3 blk(256);
  int cb_x = (int)((nx8 + 255) / 256);
  int cb_w = (int)((nw8 + 255) / 256);
  int gemm_grid = (M / GBM) * (E / GBN);  // 256, divisible by 8

  cast_f32_f16<<<cb_x, blk, 0, stream>>>(x, xh, nx8);

  cast_f32_f16<<<cb_w, blk, 0, stream>>>(Wq, wh, nw8);
  gemm256<_Float16><<<gemm_grid, 512, 0, stream>>>(xh, wh, bq, qh, M, E, E);
  cast_f32_f16<<<cb_w, blk, 0, stream>>>(Wk, wh, nw8);
  gemm256<_Float16><<<gemm_grid, 512, 0, stream>>>(xh, wh, bk, kh, M, E, E);
  cast_f32_f16<<<cb_w, blk, 0, stream>>>(Wv, wh, nw8);
  gemm256<_Float16><<<gemm_grid, 512, 0, stream>>>(xh, wh, bv, vh, M, E, E);

  rope_kernel<<<cb_x, blk, 0, stream>>>(qh, ft, S, E, nx8);
  rope_kernel<<<cb_x, blk, 0, stream>>>(kh, ft, S, E, nx8);

  flash_attn<<<Bb * H * (S / QB), blk, 0, stream>>>(qh, kh, vh, oh, Bb, H, S);

  cast_f32_f16<<<cb_w, blk, 0, stream>>>(Wo, wh, nw8);
  gemm256<float><<<gemm_grid, 512, 0, stream>>>(oh, wh, bo, (float*)d_out, M, E, E);
}

// Round 6
// 772.037 us; speedup vs baseline: 1.2136x; 1.2136x over previous
//
#include <hip/hip_runtime.h>
#include <math.h>

// ---------------------------------------------------------------------------
// Types
// ---------------------------------------------------------------------------
typedef _Float16 half8 __attribute__((ext_vector_type(8)));
typedef _Float16 half4 __attribute__((ext_vector_type(4)));
typedef float f32x4 __attribute__((ext_vector_type(4)));

struct FreqT { float f[16]; };

__device__ __forceinline__ f32x4 mfma16(half8 a, half8 b, f32x4 c) {
  return __builtin_amdgcn_mfma_f32_16x16x32_f16(a, b, c, 0, 0, 0);
}

__device__ __forceinline__ void gload_lds16(const void* g, void* l) {
  __builtin_amdgcn_global_load_lds(
      (const __attribute__((address_space(1))) void*)g,
      (__attribute__((address_space(3))) void*)l, 16, 0, 0);
}

#define S_BARRIER() __builtin_amdgcn_s_barrier()
#define WAIT_LGKM0() asm volatile("s_waitcnt lgkmcnt(0)" ::: "memory")
#define WAIT_VM8() asm volatile("s_waitcnt vmcnt(8)" ::: "memory")
#define WAIT_VM4() asm volatile("s_waitcnt vmcnt(4)" ::: "memory")
#define WAIT_VM0() asm volatile("s_waitcnt vmcnt(0)" ::: "memory")

// ---------------------------------------------------------------------------
// Cast fp32 -> fp16, 8 elems/thread
// ---------------------------------------------------------------------------
__global__ __launch_bounds__(256)
void cast_f32_f16(const float* __restrict__ in, _Float16* __restrict__ out, long n8) {
  long i = (long)blockIdx.x * blockDim.x + threadIdx.x;
  if (i >= n8) return;
  float4 a = ((const float4*)in)[2 * i];
  float4 b = ((const float4*)in)[2 * i + 1];
  half8 v;
  v[0] = (_Float16)a.x; v[1] = (_Float16)a.y; v[2] = (_Float16)a.z; v[3] = (_Float16)a.w;
  v[4] = (_Float16)b.x; v[5] = (_Float16)b.y; v[6] = (_Float16)b.z; v[7] = (_Float16)b.w;
  ((half8*)out)[i] = v;
}

// ---------------------------------------------------------------------------
// GEMM 256x256x64, 8 waves (2M x 4N), deep pipeline with counted vmcnt.
// ---------------------------------------------------------------------------
#define GBM 256
#define GBN 256
#define GBK 64

template <typename OutT>
__global__ __launch_bounds__(512, 2)
void gemm256(const _Float16* __restrict__ A, const _Float16* __restrict__ W,
             const float* __restrict__ bias, OutT* __restrict__ C,
             int M, int N, int K) {
  __shared__ __align__(16) _Float16 lds[4][GBM * GBK];

  int nwg = gridDim.x;
  int bid = blockIdx.x;
  int cpx = nwg >> 3;
  int swz = (bid & 7) * cpx + (bid >> 3);
  int ntn = N / GBN;
  int m0 = (swz / ntn) * GBM, n0 = (swz % ntn) * GBN;

  int tid = threadIdx.x, lane = tid & 63, w = tid >> 6;
  int wm = w >> 2, wn = w & 3;
  int g = lane >> 4, lc = lane & 15;

  int r8 = w * 8 + (lane >> 3);
  int cs = (((lane & 7) ^ (lane >> 3)) << 3);
  const _Float16* gA = A + (size_t)(m0 + r8) * K + cs;
  const _Float16* gB = W + (size_t)(n0 + r8) * K + cs;

#define STAGE(bi, k0) do {                                            \
    _Float16* la_ = &lds[(bi) * 2][0] + w * 512;                      \
    _Float16* lb_ = &lds[(bi) * 2 + 1][0] + w * 512;                  \
    _Pragma("unroll")                                                 \
    for (int i_ = 0; i_ < 4; ++i_) {                                  \
      gload_lds16(gA + (size_t)(i_ * 64) * K + (k0), la_ + i_ * 4096);\
      gload_lds16(gB + (size_t)(i_ * 64) * K + (k0), lb_ + i_ * 4096);\
    } } while (0)

  int aOff[8], bOff[4];
#pragma unroll
  for (int mf = 0; mf < 8; ++mf) aOff[mf] = (wm * 128 + mf * 16 + lc) * 64;
#pragma unroll
  for (int nf = 0; nf < 4; ++nf) bOff[nf] = (wn * 64 + nf * 16 + lc) * 64;
  int co0 = (((0 * 4 + g) ^ (lc & 7)) << 3);
  int co1 = (((1 * 4 + g) ^ (lc & 7)) << 3);

  half8 a0[8], a1[8], b0[4], b1[4];
  f32x4 acc[8][4] = {};

#define LOAD_SET0(bi) do {                                            \
    const _Float16* lA_ = &lds[(bi) * 2][0];                          \
    const _Float16* lB_ = &lds[(bi) * 2 + 1][0];                      \
    _Pragma("unroll")                                                 \
    for (int mf = 0; mf < 4; ++mf) {                                  \
      a0[mf * 2 + 0] = *(const half8*)&lA_[aOff[mf] + co0];           \
      a0[mf * 2 + 1] = *(const half8*)&lA_[aOff[mf] + co1];           \
    }                                                                 \
    _Pragma("unroll")                                                 \
    for (int nf = 0; nf < 2; ++nf) {                                  \
      b0[nf * 2 + 0] = *(const half8*)&lB_[bOff[nf] + co0];           \
      b0[nf * 2 + 1] = *(const half8*)&lB_[bOff[nf] + co1];           \
    } } while (0)

#define LOAD_SET1(bi) do {                                            \
    const _Float16* lA_ = &lds[(bi) * 2][0];                          \
    const _Float16* lB_ = &lds[(bi) * 2 + 1][0];                      \
    _Pragma("unroll")                                                 \
    for (int mf = 0; mf < 4; ++mf) {                                  \
      a1[mf * 2 + 0] = *(const half8*)&lA_[aOff[mf + 4] + co0];       \
      a1[mf * 2 + 1] = *(const half8*)&lA_[aOff[mf + 4] + co1];       \
    }                                                                 \
    _Pragma("unroll")                                                 \
    for (int nf = 0; nf < 2; ++nf) {                                  \
      b1[nf * 2 + 0] = *(const half8*)&lB_[bOff[nf + 2] + co0];       \
      b1[nf * 2 + 1] = *(const half8*)&lB_[bOff[nf + 2] + co1];       \
    } } while (0)

#define MFMA_Q(mq, nq, ar, br) do {                                   \
    __builtin_amdgcn_s_setprio(1);                                    \
    _Pragma("unroll")                                                 \
    for (int mf = 0; mf < 4; ++mf)                                    \
      _Pragma("unroll")                                               \
      for (int nf = 0; nf < 2; ++nf)                                  \
        _Pragma("unroll")                                             \
        for (int kk = 0; kk < 2; ++kk)                                \
          acc[(mq) * 4 + mf][(nq) * 2 + nf] =                         \
              mfma16(ar[mf * 2 + kk], br[nf * 2 + kk],                \
                     acc[(mq) * 4 + mf][(nq) * 2 + nf]);              \
    __builtin_amdgcn_s_setprio(0); } while (0)

  const int NT = K >> 6;

  STAGE(0, 0);
  STAGE(1, GBK);
  WAIT_VM8();
  S_BARRIER();
  LOAD_SET0(0);

  for (int t = 0; t < NT - 2; ++t) {
    int cur = t & 1;
    LOAD_SET1(cur);
    MFMA_Q(0, 0, a0, b0);
    MFMA_Q(0, 1, a0, b1);
    WAIT_LGKM0();
    S_BARRIER();
    STAGE(cur, (t + 2) << 6);
    MFMA_Q(1, 1, a1, b1);
    MFMA_Q(1, 0, a1, b0);
    WAIT_VM8();
    S_BARRIER();
    LOAD_SET0(cur ^ 1);
  }
  {
    int cur = (NT - 2) & 1;
    LOAD_SET1(cur);
    MFMA_Q(0, 0, a0, b0);
    MFMA_Q(0, 1, a0, b1);
    MFMA_Q(1, 1, a1, b1);
    MFMA_Q(1, 0, a1, b0);
    WAIT_VM0();
    S_BARRIER();
    LOAD_SET0(cur ^ 1);
  }
  {
    LOAD_SET1((NT - 1) & 1);
    MFMA_Q(0, 0, a0, b0);
    MFMA_Q(0, 1, a0, b1);
    MFMA_Q(1, 1, a1, b1);
    MFMA_Q(1, 0, a1, b0);
  }

  int crow = m0 + wm * 128 + g * 4;
  int ccol = n0 + wn * 64 + lc;
#pragma unroll
  for (int nf = 0; nf < 4; ++nf) {
    float bv = bias[ccol + nf * 16];
#pragma unroll
    for (int mf = 0; mf < 8; ++mf)
#pragma unroll
      for (int j = 0; j < 4; ++j)
        C[(size_t)(crow + mf * 16 + j) * N + ccol + nf * 16] =
            (OutT)(acc[mf][nf][j] + bv);
  }
#undef STAGE
#undef LOAD_SET0
#undef LOAD_SET1
#undef MFMA_Q
}

// ---------------------------------------------------------------------------
// RoPE (faithful fp32 overflow-to-zero freqs, dim=n_heads)
// ---------------------------------------------------------------------------
__global__ __launch_bounds__(256)
void rope_kernel(_Float16* __restrict__ x, FreqT ft, int Sn, int E, long n8) {
  long i = (long)blockIdx.x * blockDim.x + threadIdx.x;
  if (i >= n8) return;
  int epr = E / 8;
  int e8 = (int)(i % epr);
  int s = (int)((i / epr) % Sn);
  int fj = e8 & 15;
  float fr = ft.f[fj];
  float ang = (float)s * fr;
  float sv, cv;
  sincosf(ang, &sv, &cv);
  half8 v = ((const half8*)x)[i];
  half8 o;
#pragma unroll
  for (int p = 0; p < 4; ++p) {
    float x1 = (float)v[2 * p], x2 = (float)v[2 * p + 1];
    o[2 * p] = (_Float16)(x1 * cv - x2 * sv);
    o[2 * p + 1] = (_Float16)(x1 * sv + x2 * cv);
  }
  ((half8*)x)[i] = o;
}

// ---------------------------------------------------------------------------
// V transpose: vh [B,S,H*D] -> vt [B,H,D,S]  (per block: one (b,h,s-block 64))
// ---------------------------------------------------------------------------
__global__ __launch_bounds__(256)
void transpose_v(const _Float16* __restrict__ v, _Float16* __restrict__ vt,
                 int Hn, int Sn) {
  const int D = 128;
  const int E = Hn * D;
  __shared__ _Float16 t[64][130];   // +2 pad: column reads bank-step 1
  int spb = Sn / 64;
  int bid = blockIdx.x;
  int s0 = (bid % spb) * 64;
  int bh = bid / spb;
  int b = bh / Hn, h = bh % Hn;
  int tid = threadIdx.x;
  int r = tid >> 2, dc = (tid & 3) * 32;
  const _Float16* src = v + (size_t)(b * Sn + s0 + r) * E + h * D + dc;
#pragma unroll
  for (int i = 0; i < 4; ++i) {
    half8 x = *(const half8*)(src + i * 8);
#pragma unroll
    for (int k = 0; k < 4; ++k) {    // b32 stores (row stride 260B: 4B-aligned)
      _Float16 a0 = x[2 * k], a1 = x[2 * k + 1];
      t[r][dc + i * 8 + 2 * k] = a0;
      t[r][dc + i * 8 + 2 * k + 1] = a1;
    }
  }
  __syncthreads();
  int d = tid >> 1, sh = (tid & 1) * 32;
  half8 ov[4];
#pragma unroll
  for (int c = 0; c < 4; ++c)
#pragma unroll
    for (int j = 0; j < 8; ++j)
      ov[c][j] = t[sh + c * 8 + j][d];
  _Float16* dst = vt + ((size_t)bh * D + d) * Sn + s0 + sh;
#pragma unroll
  for (int c = 0; c < 4; ++c)
    *(half8*)(dst + c * 8) = ov[c];
}

// ---------------------------------------------------------------------------
// Flash attention (non-causal), D=128, 4 waves, QB=128 (32 q/wave), KB=64.
// Swapped QK^T (S^T = K x Q) so P rows are kv-contiguous per lane: P stores
// are b64; V pre-transposed globally, staged via swizzled global_load_lds.
// K double-buffered, V single-buffered, counted-vmcnt pipeline.
// ---------------------------------------------------------------------------
#define QB 128
#define KB 64

__global__ __launch_bounds__(256, 2)
void flash_attn(const _Float16* __restrict__ qg, const _Float16* __restrict__ kg,
                const _Float16* __restrict__ vt, _Float16* __restrict__ og,
                int Bn, int Hn, int Sn) {
  const int D = 128;
  const int E = Hn * D;

  __shared__ _Float16 Ksh[2][KB * 128];   // swizzled, 2 x 16KB
  __shared__ _Float16 Vsh[D * KB];        // V^T tile [d][kv] swizzled, 16KB
  __shared__ _Float16 Psh[4][32 * 64];    // per-wave P [q][kv] swizzled, 16KB
  __shared__ float sm[4][32];             // per-wave stat broadcast

  int qtiles = Sn / QB;
  int bid = blockIdx.x;
  int bh = bid / qtiles, qt = bid % qtiles;
  int b = bh / Hn, h = bh % Hn;

  int tid = threadIdx.x, lane = tid & 63, w = tid >> 6;
  int g = lane >> 4, lc = lane & 15;
  int lc7 = lc & 7;

  const size_t headoff = ((size_t)b * Sn) * E + (size_t)h * D;
  const _Float16* qp = qg + headoff;
  const _Float16* kp = kg + headoff;
  const _Float16* vtp = vt + (size_t)(b * Hn + h) * D * Sn;  // [d][s]

  // Q fragments (B-operand: Q[q=mf*16+lc][k])
  int q0 = qt * QB + w * 32;
  half8 aq[2][4];
#pragma unroll
  for (int mf = 0; mf < 2; ++mf)
#pragma unroll
    for (int kf = 0; kf < 4; ++kf)
      aq[mf][kf] = *(const half8*)(qp + (size_t)(q0 + mf * 16 + lc) * E + kf * 32 + g * 8);

  float mrun[2] = {-1e30f, -1e30f}, lpart[2] = {0.f, 0.f};
  f32x4 o[2][8] = {};

  const float scale = 0.08838834764831845f;  // 1/sqrt(128)

  // K staging: 4 rows/call, pre-swizzled source col
  int krow = 4 * w + (lane >> 4);
  int kcol = ((lane & 15) ^ (krow & 7)) * 8;
  const _Float16* gK = kp + (size_t)krow * E + kcol;
  // V^T staging: 8 rows/call (row=d, 64-kv rows), pre-swizzled source col
  int vrow = w * 32 + (lane >> 3);
  int vcol = ((lane & 7) ^ (vrow & 7)) * 8;
  const _Float16* gV = vtp + (size_t)vrow * Sn + vcol;

  _Float16* Pw = Psh[w];
  float* smw = sm[w];

  const int NT = Sn / KB;

  // prologue: stage K tile 0
  {
    _Float16* lK = Ksh[0] + w * 512;
#pragma unroll
    for (int i = 0; i < 4; ++i)
      gload_lds16(gK + (size_t)(16 * i) * E, lK + i * 2048);
  }
  WAIT_VM0();
  S_BARRIER();

  for (int t = 0; t < NT; ++t) {
    int c = t & 1;
    // [A] issue V(t) stage (4 calls), then K(t+1) stage (4 calls)
    {
      _Float16* lV = Vsh + w * 2048;
#pragma unroll
      for (int p = 0; p < 4; ++p)
        gload_lds16(gV + (size_t)(p * 8) * Sn + t * KB, lV + p * 512);
    }
    if (t + 1 < NT) {
      _Float16* lK = Ksh[c ^ 1] + w * 512;
#pragma unroll
      for (int i = 0; i < 4; ++i)
        gload_lds16(gK + (size_t)((t + 1) * KB + 16 * i) * E, lK + i * 2048);
    }

    // [B1] QK^T swapped: st[mf][nf] = S^T[kv-block nf][q-block mf]
    //      per lane: q = mf*16+lc, kv = nf*16 + g*4 + j
    f32x4 st[2][4] = {};
    {
      const _Float16* Kc = Ksh[c];
      __builtin_amdgcn_s_setprio(1);
#pragma unroll
      for (int kf = 0; kf < 4; ++kf) {
        half8 bk[4];
#pragma unroll
        for (int nf = 0; nf < 4; ++nf)
          bk[nf] = *(const half8*)&Kc[(nf * 16 + lc) * 128 + (((kf * 4 + g) ^ lc7) << 3)];
#pragma unroll
        for (int nf = 0; nf < 4; ++nf)
#pragma unroll
          for (int mf = 0; mf < 2; ++mf)
            st[mf][nf] = mfma16(bk[nf], aq[mf][kf], st[mf][nf]);
      }
      __builtin_amdgcn_s_setprio(0);
    }

    // [B2] softmax (transposed; stats at q = lc), defer-max THR=8
    bool resc[2];
#pragma unroll
    for (int mf = 0; mf < 2; ++mf) {
      f32x4 m4 = st[mf][0];
#pragma unroll
      for (int nf = 1; nf < 4; ++nf)
#pragma unroll
        for (int j = 0; j < 4; ++j) m4[j] = fmaxf(m4[j], st[mf][nf][j]);
      float mx = fmaxf(fmaxf(m4[0], m4[1]), fmaxf(m4[2], m4[3]));
      mx = fmaxf(mx, __shfl_xor(mx, 16));
      mx = fmaxf(mx, __shfl_xor(mx, 32));
      mx *= scale;
      resc[mf] = __any(mx > mrun[mf] + 8.f);
      if (resc[mf]) {
        float mnew = fmaxf(mrun[mf], mx);
        float r = __expf(mrun[mf] - mnew);
        mrun[mf] = mnew;
        lpart[mf] *= r;
        if (g == 0) smw[mf * 16 + lc] = r;
      }
    }
    // o-rescale (factors broadcast to PV-output lane layout)
#pragma unroll
    for (int mf = 0; mf < 2; ++mf)
      if (resc[mf]) {
        f32x4 rv = *(const f32x4*)&smw[mf * 16 + g * 4];
#pragma unroll
        for (int df = 0; df < 8; ++df)
#pragma unroll
          for (int j = 0; j < 4; ++j) o[mf][df][j] *= rv[j];
      }
    // P = exp(s*scale - m): 4 kv-consecutive values -> one b64 store
#pragma unroll
    for (int mf = 0; mf < 2; ++mf) {
      int rowoff = (mf * 16 + lc) * 64;
#pragma unroll
      for (int nf = 0; nf < 4; ++nf) {
        half4 p4;
        float ls = 0.f;
#pragma unroll
        for (int j = 0; j < 4; ++j) {
          float p = __expf(st[mf][nf][j] * scale - mrun[mf]);
          ls += p;
          p4[j] = (_Float16)p;
        }
        lpart[mf] += ls;
        *(half4*)&Pw[rowoff + ((((nf * 2 + (g >> 1)) ^ lc7) << 3) + ((g & 1) << 2))] = p4;
      }
    }

    // [C] V(t) resident (4 oldest); K(t+1)'s 4 stay in flight
    if (t + 1 < NT) { WAIT_VM4(); } else { WAIT_VM0(); }
    S_BARRIER();

    // [B3] PV: O[32,128] += P[32,64] @ V[64,128]
    __builtin_amdgcn_s_setprio(1);
#pragma unroll
    for (int kk = 0; kk < 2; ++kk) {
      int csw = ((kk * 4 + g) ^ lc7) << 3;
      half8 ap0 = *(const half8*)&Pw[lc * 64 + csw];
      half8 ap1 = *(const half8*)&Pw[(16 + lc) * 64 + csw];
#pragma unroll
      for (int df = 0; df < 8; ++df) {
        half8 bv = *(const half8*)&Vsh[(df * 16 + lc) * 64 + csw];
        o[0][df] = mfma16(ap0, bv, o[0][df]);
        o[1][df] = mfma16(ap1, bv, o[1][df]);
      }
    }
    __builtin_amdgcn_s_setprio(0);

    // [D] K(t+1) resident; all waves done with Vsh & Ksh[c]
    if (t + 1 < NT) {
      WAIT_VM0();
      S_BARRIER();
    }
  }

  // epilogue: final l across g-groups, broadcast 1/l, normalize, write
#pragma unroll
  for (int mf = 0; mf < 2; ++mf) {
    float l = lpart[mf];
    l += __shfl_xor(l, 16);
    l += __shfl_xor(l, 32);
    if (g == 0) smw[mf * 16 + lc] = 1.0f / l;
  }
  _Float16* op = og + headoff;
#pragma unroll
  for (int mf = 0; mf < 2; ++mf) {
    f32x4 li = *(const f32x4*)&smw[mf * 16 + g * 4];
#pragma unroll
    for (int j = 0; j < 4; ++j) {
      int row = q0 + mf * 16 + g * 4 + j;
#pragma unroll
      for (int df = 0; df < 8; ++df)
        op[(size_t)row * E + df * 16 + lc] = (_Float16)(o[mf][df][j] * li[j]);
    }
  }
}

// ---------------------------------------------------------------------------
// Launch
// ---------------------------------------------------------------------------
extern "C" void kernel_launch(void* const* d_in, const int* in_sizes, int n_in,
                              void* d_out, int out_size, void* d_ws, size_t ws_size,
                              hipStream_t stream) {
  const float* x  = (const float*)d_in[0];
  const float* Wq = (const float*)d_in[1];
  const float* bq = (const float*)d_in[2];
  const float* Wk = (const float*)d_in[3];
  const float* bk = (const float*)d_in[4];
  const float* Wv = (const float*)d_in[5];
  const float* bv = (const float*)d_in[6];
  const float* Wo = (const float*)d_in[7];
  const float* bo = (const float*)d_in[8];

  const int E = in_sizes[2];        // 4096
  const int M = in_sizes[0] / E;    // B*S = 4096
  const int S = 2048;
  const int Bb = M / S;             // 2
  const int H = 32;

  _Float16* xh = (_Float16*)d_ws;               // M*E (reused as attn-out)
  _Float16* wh = xh + (size_t)M * E;            // E*E (W casts; then V^T)
  _Float16* qh = wh + (size_t)E * E;            // M*E
  _Float16* kh = qh + (size_t)M * E;
  _Float16* vh = kh + (size_t)M * E;
  _Float16* oh = xh;
  _Float16* vtb = wh;                           // V^T lives in wh during attn

  FreqT ft;
  for (int j = 0; j < 16; ++j) {
    float pf = (float)pow(10000.0, (double)(2 * j));  // inf for j>=5 (faithful)
    ft.f[j] = 1.0f / (pf / 32.0f);
  }

  long nx8 = (long)M * E / 8;
  long nw8 = (long)E * E / 8;
  dim3 blk(256);
  int cb_x = (int)((nx8 + 255) / 256);
  int cb_w = (int)((nw8 + 255) / 256);
  int gemm_grid = (M / GBM) * (E / GBN);  // 256

  cast_f32_f16<<<cb_x, blk, 0, stream>>>(x, xh, nx8);

  cast_f32_f16<<<cb_w, blk, 0, stream>>>(Wq, wh, nw8);
  gemm256<_Float16><<<gemm_grid, 512, 0, stream>>>(xh, wh, bq, qh, M, E, E);
  cast_f32_f16<<<cb_w, blk, 0, stream>>>(Wk, wh, nw8);
  gemm256<_Float16><<<gemm_grid, 512, 0, stream>>>(xh, wh, bk, kh, M, E, E);
  cast_f32_f16<<<cb_w, blk, 0, stream>>>(Wv, wh, nw8);
  gemm256<_Float16><<<gemm_grid, 512, 0, stream>>>(xh, wh, bv, vh, M, E, E);

  rope_kernel<<<cb_x, blk, 0, stream>>>(qh, ft, S, E, nx8);
  rope_kernel<<<cb_x, blk, 0, stream>>>(kh, ft, S, E, nx8);

  transpose_v<<<Bb * H * (S / 64), blk, 0, stream>>>(vh, vtb, H, S);

  flash_attn<<<Bb * H * (S / QB), blk, 0, stream>>>(qh, kh, vtb, oh, Bb, H, S);

  cast_f32_f16<<<cb_w, blk, 0, stream>>>(Wo, wh, nw8);
  gemm256<float><<<gemm_grid, 512, 0, stream>>>(oh, wh, bo, (float*)d_out, M, E, E);
}